// Round 15
// baseline (4719.448 us; speedup 1.0000x reference)
//
#include <hip/hip_runtime.h>
#include <stdint.h>

// ---------------------------------------------------------------------------
// SpatioTemporalPerceiverResampler  (D=512, H=8, DH=64, NB=4, DMLP=2048,
// L=32, T=128, B=8, BT=1024, ROPE_DIM=32)
// R15: gemm256d converted to v_mfma_f32_32x32x16_bf16 (2382 vs 2075 TF
// ubench; 32 vs 64 MFMA issues per wave-tile). Same LDS layout/swizzle,
// same ds_read count, same staging; acc = [4 mf][2 nf] f32x16 with C/D map
// col=lane&31, row=(reg&3)+8*(reg>>2)+4*(lane>>5). W1 interleave unchanged
// (bit-compatible with new GEGLU pairing). All else identical to R14.
// ---------------------------------------------------------------------------

typedef short    bf16x8 __attribute__((ext_vector_type(8)));
typedef float    f32x4  __attribute__((ext_vector_type(4)));
typedef float    f32x16 __attribute__((ext_vector_type(16)));
typedef uint16_t u16;

__device__ __forceinline__ float bf2f(uint32_t u) {
  union { uint32_t i; float f; } x; x.i = u << 16; return x.f;
}
__device__ __forceinline__ u16 f2bf(float f) {
  union { float f; uint32_t i; } x; x.f = f;
  return (u16)((x.i + 0x7fffu + ((x.i >> 16) & 1u)) >> 16);  // RNE
}
__device__ __forceinline__ float gelu_t(float x) {  // jax.nn.gelu approximate=True
  float u = 0.7978845608028654f * (x + 0.044715f * x * x * x);
  float t = 1.f - 2.f / (__expf(2.f * u) + 1.f);
  return 0.5f * x * (1.f + t);
}
// r_x = (b*L + l)*T + t  ->  lat row (b*T + t)*L + l     (L=32, T=128)
template<int RMAP>
__device__ __forceinline__ int maprow(int r) {
  if (RMAP == 0) return r;
  int b = r >> 12, rem = r & 4095;
  return ((b << 7) + (rem & 127)) * 32 + (rem >> 7);
}
__device__ __forceinline__ void glds16(const u16* g, u16* l) {
  __builtin_amdgcn_global_load_lds((const __attribute__((address_space(1))) uint32_t*)(g),
                                   (__attribute__((address_space(3))) uint32_t*)(l),
                                   16, 0, 0);
}

// ---------------------------------------------------------------------------
__global__ __launch_bounds__(256) void transpose_cast(const float* __restrict__ src,
                                                      u16* __restrict__ dst,
                                                      int R, int C, size_t zsD) {
  src += (size_t)blockIdx.z * R * C;
  dst += (size_t)blockIdx.z * zsD;
  __shared__ float t[32][33];
  int c0 = blockIdx.x * 32, r0 = blockIdx.y * 32;
  int tx = threadIdx.x & 31, ty = threadIdx.x >> 5;
#pragma unroll
  for (int i = 0; i < 32; i += 8) t[ty + i][tx] = src[(size_t)(r0 + ty + i) * C + c0 + tx];
  __syncthreads();
#pragma unroll
  for (int i = 0; i < 32; i += 8)
    dst[(size_t)(c0 + ty + i) * R + r0 + tx] = f2bf(t[tx][ty + i]);
}

// w1 (512 x 4096) -> w1t (4096 x 512), GEGLU interleave (R8-proven; also
// bit-compatible with the 32x32 fragment pairing: wn=(c>>6)&3, nf=(c>>5)&1):
// dst row c: src col (c>>8)*128 + ((c>>6)&3)*32 + (c&31) + (c&32 ? 2048 : 0)
__global__ __launch_bounds__(256) void transpose_w1(const float* __restrict__ src,
                                                    u16* __restrict__ dst) {
  src += (size_t)blockIdx.z * 512 * 4096;
  dst += (size_t)blockIdx.z * 512 * 4096;
  __shared__ float t[32][33];
  int c0 = blockIdx.x * 32, r0 = blockIdx.y * 32;
  int m0 = (c0 >> 8) * 128 + ((c0 >> 6) & 3) * 32 + ((c0 & 32) ? 2048 : 0);
  int tx = threadIdx.x & 31, ty = threadIdx.x >> 5;
#pragma unroll
  for (int i = 0; i < 32; i += 8) t[ty + i][tx] = src[(size_t)(r0 + ty + i) * 4096 + m0 + tx];
  __syncthreads();
#pragma unroll
  for (int i = 0; i < 32; i += 8)
    dst[(size_t)(c0 + ty + i) * 512 + r0 + tx] = f2bf(t[tx][ty + i]);
}

// ---------------------------------------------------------------------------
__global__ void rope_init(float* cosT, float* sinT) {
  int idx = blockIdx.x * 256 + threadIdx.x;
  if (idx < 128 * 16) {
    int t = idx >> 4, j = idx & 15;
    float inv = __expf(-logf(10000.f) * (float)j / 16.f);
    float a = (float)t * inv;
    cosT[idx] = cosf(a);
    sinT[idx] = sinf(a);
  }
}

__global__ __launch_bounds__(256) void init_lat(const float* __restrict__ ql,
                                                float* __restrict__ lat) {
  size_t i = (size_t)blockIdx.x * 256 + threadIdx.x;  // float4 index
  int r = (int)(i >> 7), cw = (int)(i & 127);
  int l = r & 31;
  ((float4*)lat)[i] = ((const float4*)ql)[l * 128 + cw];
}

// ---------------------------------------------------------------------------
// rms helper (one wave per row of 512)
__device__ __forceinline__ void rms_row_body(const float* __restrict__ src,
                                             const float* __restrict__ g,
                                             u16* __restrict__ out,
                                             int srow, int orow, int lane) {
  const float4* p = (const float4*)(src + (size_t)srow * 512);
  float4 v0 = p[lane * 2], v1 = p[lane * 2 + 1];
  float ss = v0.x * v0.x + v0.y * v0.y + v0.z * v0.z + v0.w * v0.w +
             v1.x * v1.x + v1.y * v1.y + v1.z * v1.z + v1.w * v1.w;
#pragma unroll
  for (int m = 1; m < 64; m <<= 1) ss += __shfl_xor(ss, m);
  const float rs = rsqrtf(ss * (1.f / 512.f) + 1e-6f);
  const float4* gp = (const float4*)g;
  float4 g0 = gp[lane * 2], g1 = gp[lane * 2 + 1];
  u16 rb[8];
  rb[0] = f2bf(v0.x * rs * g0.x); rb[1] = f2bf(v0.y * rs * g0.y);
  rb[2] = f2bf(v0.z * rs * g0.z); rb[3] = f2bf(v0.w * rs * g0.w);
  rb[4] = f2bf(v1.x * rs * g1.x); rb[5] = f2bf(v1.y * rs * g1.y);
  rb[6] = f2bf(v1.z * rs * g1.z); rb[7] = f2bf(v1.w * rs * g1.w);
  *(int4*)(out + (size_t)orow * 512 + lane * 8) = *(int4*)rb;
}

template<int RMAP>
__global__ __launch_bounds__(256) void rms_rows(const float* __restrict__ src,
                                                const float* __restrict__ g,
                                                u16* __restrict__ out) {
  const int wid = threadIdx.x >> 6, lane = threadIdx.x & 63;
  const int row = (blockIdx.x << 2) + wid;
  rms_row_body(src, g, out, maprow<RMAP>(row), row, lane);
}

// merged CA norms: blocks [0,8192): l_n (lat->xn); [8192,24576): s_n.
__global__ __launch_bounds__(256) void rms_ca(const float* __restrict__ lat,
                                              const float* __restrict__ source,
                                              const float* __restrict__ g0,
                                              const float* __restrict__ g1,
                                              u16* __restrict__ xn,
                                              u16* __restrict__ shat) {
  const int wid = threadIdx.x >> 6, lane = threadIdx.x & 63;
  if (blockIdx.x < 8192) {
    const int row = (blockIdx.x << 2) + wid;
    rms_row_body(lat, g0, xn, row, row, lane);
  } else {
    const int row = ((blockIdx.x - 8192) << 2) + wid;
    rms_row_body(source, g1, shat, row, row, lane);
  }
}

// ---------------------------------------------------------------------------
// gemm256d (R15): 256x256 tile, BK=64, 8 waves (2M x 4N), per-wave C 128x64
// as [4 mf][2 nf] 32x32 fragments, v_mfma_f32_32x32x16_bf16 (4 k-steps/tile,
// 8 MFMA/phase). Double-buffered A/B with compile-time slot parity, frag
// ping-pong one phase ahead (phase p == mf), NO mid-tile barriers, gate =
// vmcnt(0)+barrier per K-tile. XOR swizzle (rx=(lane&7)<<3 both operands),
// setprio, XCD swizzle. C/D map: col=lane&31, row=(reg&3)+8*(reg>>2)+4*hi.
// EPI: 0 bf16; 1 +bias cols<512; 2 latF[maprow]+=; 3 GEGLU->h2[.][2048];
//      4 TA QKV route. AMAP: 1 = CA kv row map.
// ---------------------------------------------------------------------------
template<int EPI, int RMAP, int AMAP>
__global__ __launch_bounds__(512, 2) void gemm256d(const u16* __restrict__ A,
                                                   const u16* __restrict__ A2,
                                                   const u16* __restrict__ Bt,
                                                   u16* __restrict__ outH,
                                                   u16* __restrict__ outH2,
                                                   float* __restrict__ latF,
                                                   const float* __restrict__ bias,
                                                   int N, int K, int ntn, int nb) {
  __shared__ __align__(16) u16 Ab[2][256 * 64];   // 64 KiB
  __shared__ __align__(16) u16 Bb[2][256 * 64];   // 64 KiB
  const int tid = threadIdx.x;
  const int NBk = gridDim.x;
  const int sb = (blockIdx.x & 7) * (NBk >> 3) + (blockIdx.x >> 3);  // XCD swz
  const int m0 = (sb / ntn) << 8;
  const int n0 = (sb % ntn) << 8;
  const int wid = tid >> 6, lane = tid & 63;
  const int wm = wid >> 2, wn = wid & 3;
  const int l5 = lane & 31, hi = lane >> 5;
  const int rx = (lane & 7) << 3;  // read-side col XOR (elems)
  const int nkt = K >> 6;          // even for all shapes used (8 or 32)

  auto stageA = [&](int kt, int slot, int h) {
#pragma unroll
    for (int i = 0; i < 2; ++i) {
      const int e = ((h * 2 + i) * 512 + tid) * 8;
      const int r = e >> 6;
      const int cs = (e & 63) ^ ((r & 7) << 3);
      const u16* src;
      if constexpr (AMAP == 0) {
        src = A + (size_t)(m0 + r) * K + kt * 64 + cs;
      } else {
        const int R = m0 + r;
        const int n_ = R / 96;
        const int j = R - n_ * 96;
        src = (j < 64) ? A  + ((size_t)((nb + n_) * 64 + j)) * 512 + kt * 64 + cs
                       : A2 + ((size_t)((nb + n_) * 32 + (j - 64))) * 512 + kt * 64 + cs;
      }
      glds16(src, &Ab[slot][e]);
    }
  };
  auto stageB = [&](int kt, int slot, int h) {
#pragma unroll
    for (int i = 0; i < 2; ++i) {
      const int e = ((h * 2 + i) * 512 + tid) * 8;
      const int r = e >> 6;
      const int cs = (e & 63) ^ ((r & 7) << 3);
      glds16(Bt + (size_t)(n0 + r) * K + kt * 64 + cs, &Bb[slot][e]);
    }
  };

  bf16x8 bfr[4][2];                 // [ks][nf], whole K-tile
  bf16x8 afrA[4], afrB_[4];         // [ks] for one mf (ping-pong by phase)
  auto readAfr = [&](bf16x8 (&dst)[4], const u16* Abase, int mf) {
    const int rw = wm * 128 + mf * 32 + l5;
#pragma unroll
    for (int ks = 0; ks < 4; ++ks)
      dst[ks] = *(const bf16x8*)&Abase[rw * 64 + ((ks * 16 + hi * 8) ^ rx)];
  };
  auto readBfr = [&](const u16* Bbase) {
#pragma unroll
    for (int nf = 0; nf < 2; ++nf) {
      const int rw = wn * 64 + nf * 32 + l5;
#pragma unroll
      for (int ks = 0; ks < 4; ++ks)
        bfr[ks][nf] = *(const bf16x8*)&Bbase[rw * 64 + ((ks * 16 + hi * 8) ^ rx)];
    }
  };

  f32x16 acc[4][2];
#pragma unroll
  for (int i = 0; i < 4; ++i)
#pragma unroll
    for (int j = 0; j < 2; ++j)
#pragma unroll
      for (int e = 0; e < 16; ++e) acc[i][j][e] = 0.f;

  // prologue: stage tile 0 into slot 0; drain; pre-read frags.
  stageA(0, 0, 0); stageA(0, 0, 1);
  stageB(0, 0, 0); stageB(0, 0, 1);
  asm volatile("s_waitcnt vmcnt(0)" ::: "memory");
  __builtin_amdgcn_s_barrier();
  asm volatile("" ::: "memory");
  readBfr(&Bb[0][0]);
  readAfr(afrA, &Ab[0][0], 0);

  for (int kt0 = 0; kt0 < nkt; kt0 += 2) {
#pragma unroll
    for (int par = 0; par < 2; ++par) {       // par == buffer slot (compile-time)
      const int vk = kt0 + par;
      const u16* Abase = &Ab[par][0];
      const bool pf = (vk + 1 < nkt);
#pragma unroll
      for (int p = 0; p < 4; ++p) {           // phase p == mf
        if (p == 0 && pf) { stageB(vk + 1, par ^ 1, 0); stageB(vk + 1, par ^ 1, 1); }
        if (p == 1 && pf) { stageA(vk + 1, par ^ 1, 0); stageA(vk + 1, par ^ 1, 1); }
        if (p < 3) {
          if ((p & 1) == 0) readAfr(afrB_, Abase, p + 1);
          else              readAfr(afrA,  Abase, p + 1);
        }
        __builtin_amdgcn_s_setprio(1);
        if ((p & 1) == 0) {
#pragma unroll
          for (int nf = 0; nf < 2; ++nf)
#pragma unroll
            for (int ks = 0; ks < 4; ++ks)
              acc[p][nf] = __builtin_amdgcn_mfma_f32_32x32x16_bf16(
                  afrA[ks], bfr[ks][nf], acc[p][nf], 0, 0, 0);
        } else {
#pragma unroll
          for (int nf = 0; nf < 2; ++nf)
#pragma unroll
            for (int ks = 0; ks < 4; ++ks)
              acc[p][nf] = __builtin_amdgcn_mfma_f32_32x32x16_bf16(
                  afrB_[ks], bfr[ks][nf], acc[p][nf], 0, 0, 0);
        }
        __builtin_amdgcn_s_setprio(0);
        // no mid-tile barriers (R12 win); gate per K-tile:
        if (p == 3 && pf) {
          asm volatile("s_waitcnt vmcnt(0)" ::: "memory");
          __builtin_amdgcn_s_barrier();
          asm volatile("" ::: "memory");
          readBfr(&Bb[par ^ 1][0]);
          readAfr(afrA, &Ab[par ^ 1][0], 0);
        }
      }
    }
  }

  // ---- epilogue (C/D: col = lane&31, row = (reg&3)+8*(reg>>2)+4*hi) ----
  if constexpr (EPI == 3) {
    const int t128 = n0 >> 1;
    const int hcol = t128 + wn * 32 + l5;
#pragma unroll
    for (int mf = 0; mf < 4; ++mf)
#pragma unroll
      for (int reg = 0; reg < 16; ++reg) {
        const int row = m0 + wm * 128 + mf * 32 + (reg & 3) + 8 * (reg >> 2) + 4 * hi;
        outH[(size_t)row * 2048 + hcol] = f2bf(acc[mf][0][reg] * gelu_t(acc[mf][1][reg]));
      }
  } else if constexpr (EPI == 2) {
#pragma unroll
    for (int mf = 0; mf < 4; ++mf)
#pragma unroll
      for (int nf = 0; nf < 2; ++nf) {
        const int col = n0 + wn * 64 + nf * 32 + l5;
#pragma unroll
        for (int reg = 0; reg < 16; ++reg) {
          const int row = m0 + wm * 128 + mf * 32 + (reg & 3) + 8 * (reg >> 2) + 4 * hi;
          latF[(size_t)maprow<RMAP>(row) * 512 + col] += acc[mf][nf][reg];
        }
      }
  } else if constexpr (EPI == 4) {
    // TA QKV route (col span per frag is 32 wide, never straddles 512-blocks)
    float bv2[2];
#pragma unroll
    for (int nf = 0; nf < 2; ++nf) {
      const int col = n0 + wn * 64 + nf * 32 + l5;
      bv2[nf] = (col >= 512 && col < 1024) ? bias[col - 512] : 0.f;
    }
#pragma unroll
    for (int mf = 0; mf < 4; ++mf)
#pragma unroll
      for (int nf = 0; nf < 2; ++nf) {
        const int col = n0 + wn * 64 + nf * 32 + l5;
#pragma unroll
        for (int reg = 0; reg < 16; ++reg) {
          const int row = m0 + wm * 128 + mf * 32 + (reg & 3) + 8 * (reg >> 2) + 4 * hi;
          const float v = acc[mf][nf][reg] + bv2[nf];
          if (col < 512) outH[(size_t)row * 512 + col] = f2bf(v);
          else           outH2[(size_t)row * 1024 + col - 512] = f2bf(v);
        }
      }
  } else {
    float bv2[2];
    if constexpr (EPI == 1) {
#pragma unroll
      for (int nf = 0; nf < 2; ++nf)
        bv2[nf] = (n0 < 512) ? bias[n0 + wn * 64 + nf * 32 + l5] : 0.f;
    }
#pragma unroll
    for (int mf = 0; mf < 4; ++mf)
#pragma unroll
      for (int nf = 0; nf < 2; ++nf) {
        const int col = n0 + wn * 64 + nf * 32 + l5;
#pragma unroll
        for (int reg = 0; reg < 16; ++reg) {
          const int row = m0 + wm * 128 + mf * 32 + (reg & 3) + 8 * (reg >> 2) + 4 * hi;
          float v = acc[mf][nf][reg];
          if constexpr (EPI == 1) v += bv2[nf];
          outH[(size_t)row * N + col] = f2bf(v);
        }
      }
  }
}

// ---------------------------------------------------------------------------
// Cross-attention R6: block per (n_local,h), n = nb + n_local. Lq=32, Lk=96.
// ---------------------------------------------------------------------------
__global__ __launch_bounds__(256) void attn_ca(const u16* q,
                                               const u16* __restrict__ kv,
                                               u16* o, int nb) {
  union __align__(16) SM {
    struct { u16 Qs[32][72]; u16 Ks[96][72]; } qk;
    u16 Pb[32][104];
  };
  __shared__ SM sm;
  __shared__ __align__(16) u16 Vt[64][104];
  __shared__ float pmax[2][32];
  __shared__ float psum[2][32];
  const int nl = blockIdx.x, n = nb + nl, h = blockIdx.y, tid = threadIdx.x;

  {
    int r = tid >> 3, c = (tid & 7) * 8;
    *(int4*)&sm.qk.Qs[r][c] = *(const int4*)&q[((size_t)n * 32 + r) * 512 + h * 64 + c];
  }
#pragma unroll
  for (int i = 0; i < 3; ++i) {
    int idx = i * 256 + tid;
    int r = idx >> 3, c = (idx & 7) * 8;
    *(int4*)&sm.qk.Ks[r][c] = *(const int4*)&kv[((size_t)nl * 96 + r) * 1024 + h * 64 + c];
  }
#pragma unroll
  for (int i = 0; i < 3; ++i) {
    int idx = i * 256 + tid;
    int dg = idx / 96, t = idx - dg * 96;
    int4 pv = *(const int4*)&kv[((size_t)nl * 96 + t) * 1024 + 512 + h * 64 + dg * 8];
    const u16* pu = (const u16*)&pv;
#pragma unroll
    for (int e = 0; e < 8; ++e) Vt[dg * 8 + e][t] = pu[e];
  }
  __syncthreads();

  const int wid = tid >> 6, lane = tid & 63, lr = lane & 15, lg = lane >> 4;
  const int m0 = (wid & 1) * 16, wnq = wid >> 1, nbc = wnq * 48;

  f32x4 sa[3];
#pragma unroll
  for (int f = 0; f < 3; ++f) sa[f] = (f32x4){0.f, 0.f, 0.f, 0.f};
#pragma unroll
  for (int ks = 0; ks < 2; ++ks) {
    bf16x8 a = *(const bf16x8*)&sm.qk.Qs[m0 + lr][ks * 32 + lg * 8];
#pragma unroll
    for (int f = 0; f < 3; ++f) {
      bf16x8 bb = *(const bf16x8*)&sm.qk.Ks[nbc + f * 16 + lr][ks * 32 + lg * 8];
      sa[f] = __builtin_amdgcn_mfma_f32_16x16x32_bf16(a, bb, sa[f], 0, 0, 0);
    }
  }

#pragma unroll
  for (int j = 0; j < 4; ++j) {
    float m = fmaxf(fmaxf(sa[0][j], sa[1][j]), sa[2][j]);
    m = fmaxf(m, __shfl_xor(m, 1));
    m = fmaxf(m, __shfl_xor(m, 2));
    m = fmaxf(m, __shfl_xor(m, 4));
    m = fmaxf(m, __shfl_xor(m, 8));
    if (lr == 0) pmax[wnq][m0 + lg * 4 + j] = m;
  }
  __syncthreads();
#pragma unroll
  for (int j = 0; j < 4; ++j) {
    const int row = m0 + lg * 4 + j;
    const float m = fmaxf(pmax[0][row], pmax[1][row]);
    float s = 0.f;
#pragma unroll
    for (int f = 0; f < 3; ++f) {
      float p = __expf(0.125f * (sa[f][j] - m));
      sa[f][j] = p;
      s += p;
    }
    s += __shfl_xor(s, 1); s += __shfl_xor(s, 2); s += __shfl_xor(s, 4); s += __shfl_xor(s, 8);
    if (lr == 0) psum[wnq][row] = s;
  }
#pragma unroll
  for (int f = 0; f < 3; ++f)
#pragma unroll
    for (int j = 0; j < 4; ++j)
      sm.Pb[m0 + lg * 4 + j][nbc + f * 16 + lr] = f2bf(sa[f][j]);
  __syncthreads();

  const int n0d = wnq * 32;
  f32x4 oa[2];
#pragma unroll
  for (int f = 0; f < 2; ++f) oa[f] = (f32x4){0.f, 0.f, 0.f, 0.f};
#pragma unroll
  for (int ks = 0; ks < 3; ++ks) {
    bf16x8 a = *(const bf16x8*)&sm.Pb[m0 + lr][ks * 32 + lg * 8];
#pragma unroll
    for (int f = 0; f < 2; ++f) {
      bf16x8 bb = *(const bf16x8*)&Vt[n0d + f * 16 + lr][ks * 32 + lg * 8];
      oa[f] = __builtin_amdgcn_mfma_f32_16x16x32_bf16(a, bb, oa[f], 0, 0, 0);
    }
  }
#pragma unroll
  for (int j = 0; j < 4; ++j) {
    const int row = m0 + lg * 4 + j;
    const float inv = 1.f / (psum[0][row] + psum[1][row]);
#pragma unroll
    for (int f = 0; f < 2; ++f)
      o[((size_t)n * 32 + row) * 512 + h * 64 + n0d + f * 16 + lr] = f2bf(oa[f][j] * inv);
  }
}

// ---------------------------------------------------------------------------
// Temporal attention R6 with RoPE: block per (n,h), n in [0,256). T=128.
// ---------------------------------------------------------------------------
__global__ __launch_bounds__(256) void attn_ta(const u16* q,
                                               const u16* __restrict__ kv,
                                               const float* __restrict__ cosT,
                                               const float* __restrict__ sinT,
                                               u16* o) {
  union __align__(16) SM {
    struct { u16 Qs[128][72]; u16 Ks[128][72]; } qk;
    u16 Pb[128][136];
  };
  __shared__ SM sm;
  __shared__ __align__(16) u16 Vt[64][136];
  __shared__ float pmax[2][128];
  __shared__ float psum[2][128];
  const int n = blockIdx.x, h = blockIdx.y, tid = threadIdx.x;

#pragma unroll
  for (int i = 0; i < 16; ++i) {
    int idx = i * 256 + tid;
    int t = idx >> 5, pr = idx & 31;
    uint32_t uq = *(const uint32_t*)&q[((size_t)n * 128 + t) * 512 + h * 64 + pr * 2];
    uint32_t uk = *(const uint32_t*)&kv[((size_t)n * 128 + t) * 1024 + h * 64 + pr * 2];
    float q1 = bf2f(uq & 0xffff), q2 = bf2f(uq >> 16);
    float k1 = bf2f(uk & 0xffff), k2 = bf2f(uk >> 16);
    if (pr < 16) {
      float c = cosT[t * 16 + pr], s = sinT[t * 16 + pr];
      float a;
      a = q1 * c - q2 * s; q2 = q1 * s + q2 * c; q1 = a;
      a = k1 * c - k2 * s; k2 = k1 * s + k2 * c; k1 = a;
    }
    sm.qk.Qs[t][pr * 2] = f2bf(q1); sm.qk.Qs[t][pr * 2 + 1] = f2bf(q2);
    sm.qk.Ks[t][pr * 2] = f2bf(k1); sm.qk.Ks[t][pr * 2 + 1] = f2bf(k2);
  }
#pragma unroll
  for (int i = 0; i < 4; ++i) {
    int idx = i * 256 + tid;
    int t = idx & 127, d0 = (idx >> 7) * 8;
    int4 pv = *(const int4*)&kv[((size_t)n * 128 + t) * 1024 + 512 + h * 64 + d0];
    const u16* pu = (const u16*)&pv;
#pragma unroll
    for (int e = 0; e < 8; ++e) Vt[d0 + e][t] = pu[e];
  }
  __syncthreads();

  const int wid = tid >> 6, lane = tid & 63, lr = lane & 15, lg = lane >> 4;
  const int wm = wid >> 1, wn = wid & 1;
  const int rbase = wm * 64;

  f32x4 sa[4][4];
#pragma unroll
  for (int i = 0; i < 4; ++i)
#pragma unroll
    for (int j = 0; j < 4; ++j) sa[i][j] = (f32x4){0.f, 0.f, 0.f, 0.f};
#pragma unroll
  for (int ks = 0; ks < 2; ++ks) {
    bf16x8 av[4], bv[4];
#pragma unroll
    for (int im = 0; im < 4; ++im)
      av[im] = *(const bf16x8*)&sm.qk.Qs[rbase + im * 16 + lr][ks * 32 + lg * 8];
#pragma unroll
    for (int in = 0; in < 4; ++in)
      bv[in] = *(const bf16x8*)&sm.qk.Ks[wn * 64 + in * 16 + lr][ks * 32 + lg * 8];
#pragma unroll
    for (int im = 0; im < 4; ++im)
#pragma unroll
      for (int in = 0; in < 4; ++in)
        sa[im][in] = __builtin_amdgcn_mfma_f32_16x16x32_bf16(av[im], bv[in], sa[im][in], 0, 0, 0);
  }

#pragma unroll
  for (int im = 0; im < 4; ++im)
#pragma unroll
    for (int j = 0; j < 4; ++j) {
      float m = fmaxf(fmaxf(sa[im][0][j], sa[im][1][j]), fmaxf(sa[im][2][j], sa[im][3][j]));
      m = fmaxf(m, __shfl_xor(m, 1));
      m = fmaxf(m, __shfl_xor(m, 2));
      m = fmaxf(m, __shfl_xor(m, 4));
      m = fmaxf(m, __shfl_xor(m, 8));
      if (lr == 0) pmax[wn][rbase + im * 16 + lg * 4 + j] = m;
    }
  __syncthreads();
#pragma unroll
  for (int im = 0; im < 4; ++im)
#pragma unroll
    for (int j = 0; j < 4; ++j) {
      const int row = rbase + im * 16 + lg * 4 + j;
      const float m = fmaxf(pmax[0][row], pmax[1][row]);
      float s = 0.f;
#pragma unroll
      for (int in = 0; in < 4; ++in) {
        float p = __expf(0.125f * (sa[im][in][j] - m));
        sa[im][in][j] = p;
        s += p;
      }
      s += __shfl_xor(s, 1); s += __shfl_xor(s, 2); s += __shfl_xor(s, 4); s += __shfl_xor(s, 8);
      if (lr == 0) psum[wn][row] = s;
    }
#pragma unroll
  for (int im = 0; im < 4; ++im)
#pragma unroll
    for (int in = 0; in < 4; ++in)
#pragma unroll
      for (int j = 0; j < 4; ++j)
        sm.Pb[rbase + im * 16 + lg * 4 + j][wn * 64 + in * 16 + lr] = f2bf(sa[im][in][j]);
  __syncthreads();

  f32x4 oa[2][4];
#pragma unroll
  for (int i = 0; i < 2; ++i)
#pragma unroll
    for (int j = 0; j < 4; ++j) oa[i][j] = (f32x4){0.f, 0.f, 0.f, 0.f};
#pragma unroll
  for (int ks = 0; ks < 4; ++ks) {
    bf16x8 av[2], bv[4];
#pragma unroll
    for (int im = 0; im < 2; ++im)
      av[im] = *(const bf16x8*)&sm.Pb[wid * 32 + im * 16 + lr][ks * 32 + lg * 8];
#pragma unroll
    for (int in = 0; in < 4; ++in)
      bv[in] = *(const bf16x8*)&Vt[in * 16 + lr][ks * 32 + lg * 8];
#pragma unroll
    for (int im = 0; im < 2; ++im)
#pragma unroll
      for (int in = 0; in < 4; ++in)
        oa[im][in] = __builtin_amdgcn_mfma_f32_16x16x32_bf16(av[im], bv[in], oa[im][in], 0, 0, 0);
  }
#pragma unroll
  for (int im = 0; im < 2; ++im)
#pragma unroll
    for (int j = 0; j < 4; ++j) {
      const int qi = wid * 32 + im * 16 + lg * 4 + j;
      const float inv = 1.f / (psum[0][qi] + psum[1][qi]);
#pragma unroll
      for (int in = 0; in < 4; ++in)
        o[((size_t)n * 128 + qi) * 512 + h * 64 + in * 16 + lr] = f2bf(oa[im][in][j] * inv);
    }
}

// ---------------------------------------------------------------------------
extern "C" void kernel_launch(void* const* d_in, const int* in_sizes, int n_in,
                              void* d_out, int out_size, void* d_ws, size_t ws_size,
                              hipStream_t stream) {
  const float* source = (const float*)d_in[0];
  const float* qlat   = (const float*)d_in[1];
  const float* ca_ln  = (const float*)d_in[2];
  const float* ca_wq  = (const float*)d_in[3];
  const float* ca_wk  = (const float*)d_in[4];
  const float* ca_bk  = (const float*)d_in[5];
  const float* ca_wv  = (const float*)d_in[6];
  const float* ca_wo  = (const float*)d_in[7];
  const float* ca_w1  = (const float*)d_in[8];
  const float* ca_w2  = (const float*)d_in[9];
  const float* ta_ln  = (const float*)d_in[10];
  const float* ta_wq  = (const float*)d_in[11];
  const float* ta_wk  = (const float*)d_in[12];
  const float* ta_bk  = (const float*)d_in[13];
  const float* ta_wv  = (const float*)d_in[14];
  const float* ta_wo  = (const float*)d_in[15];
  const float* ta_w1  = (const float*)d_in[16];
  const float* ta_w2  = (const float*)d_in[17];
  float* lat = (float*)d_out;  // residual stream lives in d_out
  char* ws = (char*)d_ws;
  (void)in_sizes; (void)n_in; (void)out_size;

  if (ws_size < 251674624ull) return;  // known-good guard from R2

  const size_t WQ = 512 * 512, W1SZ = (size_t)512 * 4096, W2SZ = (size_t)2048 * 512;
  const size_t O_CA_WQ = 0,
               O_CA_KV = 4 * WQ,
               O_CA_WO = 12 * WQ,
               O_CA_W1 = 16 * WQ,
               O_CA_W2 = O_CA_W1 + 4 * W1SZ,
               O_TA_QKV = O_CA_W2 + 4 * W2SZ,      // [wq|wk|wv] per block, 3WQ each
               O_TA_WO = O_TA_QKV + 12 * WQ,
               O_TA_W1 = O_TA_WO + 4 * WQ,
               O_TA_W2 = O_TA_W1 + 4 * W1SZ;  // ends at 128*WQ = 67,108,864 B

  u16*   W    = (u16*)ws;                    // [0, 67,108,864)  weights (exact)
  u16*   xn   = (u16*)(ws + 67108864);       // 32 MiB
  u16*   shat = (u16*)(ws + 100663296);      // 64 MiB (CA s_n; TA fused KV; h2 head)
  u16*   qb   = (u16*)(ws + 167772160);      // 32 MiB (q / attn out)
  u16*   kvb  = (u16*)(ws + 201326592);      // 48 MiB (CA fused K|V chunk)
  u16*   h2   = shat;                        // MLP hidden 128 MiB
  u16*   takv = shat;                        // TA fused KV 64 MiB
  float* cosT = (float*)(ws + 251658240);    // 8 KiB  (tail gap, within guard)
  float* sinT = (float*)(ws + 251666432);    // 8 KiB

  transpose_cast<<<dim3(16, 16, 4), 256, 0, stream>>>(ca_wq, W + O_CA_WQ, 512, 512, WQ);
  transpose_cast<<<dim3(16, 16, 4), 256, 0, stream>>>(ca_wk, W + O_CA_KV, 512, 512, 2 * WQ);
  transpose_cast<<<dim3(16, 16, 4), 256, 0, stream>>>(ca_wv, W + O_CA_KV + WQ, 512, 512, 2 * WQ);
  transpose_cast<<<dim3(16, 16, 4), 256, 0, stream>>>(ca_wo, W + O_CA_WO, 512, 512, WQ);
  transpose_w1 <<<dim3(128, 16, 4), 256, 0, stream>>>(ca_w1, W + O_CA_W1);
  transpose_cast<<<dim3(16, 64, 4), 256, 0, stream>>>(ca_w2, W + O_CA_W2, 2048, 512, W2SZ);
  transpose_cast<<<dim3(16, 16, 4), 256, 0, stream>>>(ta_wq, W + O_TA_QKV, 512, 512, 3 * WQ);
  transpose_cast<<<dim3(16, 16, 4), 256, 0, stream>>>(ta_wk, W + O_TA_QKV + WQ, 512, 512, 3 * WQ);
  transpose_cast<<<dim3(16, 16, 4), 256, 0, stream>>>(ta_wv, W + O_TA_QKV + 2 * WQ, 512, 512, 3 * WQ);
  transpose_cast<<<dim3(16, 16, 4), 256, 0, stream>>>(ta_wo, W + O_TA_WO, 512, 512, WQ);
  transpose_w1 <<<dim3(128, 16, 4), 256, 0, stream>>>(ta_w1, W + O_TA_W1);
  transpose_cast<<<dim3(16, 64, 4), 256, 0, stream>>>(ta_w2, W + O_TA_W2, 2048, 512, W2SZ);
  rope_init<<<8, 256, 0, stream>>>(cosT, sinT);
  init_lat<<<16384, 256, 0, stream>>>(qlat, lat);

  for (int b = 0; b < 4; ++b) {
    const u16* wqt   = W + O_CA_WQ + (size_t)b * WQ;
    const u16* wkvt  = W + O_CA_KV + (size_t)b * 2 * WQ;
    const u16* wot   = W + O_CA_WO + (size_t)b * WQ;
    const u16* w1t   = W + O_CA_W1 + (size_t)b * W1SZ;
    const u16* w2t   = W + O_CA_W2 + (size_t)b * W2SZ;
    const u16* tqkvt = W + O_TA_QKV + (size_t)b * 3 * WQ;
    const u16* twot  = W + O_TA_WO + (size_t)b * WQ;
    const u16* tw1t  = W + O_TA_W1 + (size_t)b * W1SZ;
    const u16* tw2t  = W + O_TA_W2 + (size_t)b * W2SZ;

    // ---- cross attention ----
    rms_ca<<<24576, 256, 0, stream>>>(lat, source, ca_ln + b * 1536, ca_ln + b * 1536 + 512, xn, shat);
    gemm256d<0, 0, 0><<<256, 512, 0, stream>>>(xn, nullptr, wqt, qb, nullptr, nullptr, nullptr, 512, 512, 2, 0);
    for (int c = 0; c < 4; ++c) {  // fused K|V + attention per 256-batch chunk
      gemm256d<1, 0, 1><<<384, 512, 0, stream>>>(shat, xn, wkvt, kvb, nullptr, nullptr, ca_bk + b * 512, 1024, 512, 4, c * 256);
      attn_ca<<<dim3(256, 8), 256, 0, stream>>>(qb, kvb, qb, c * 256);
    }
    gemm256d<2, 0, 0><<<256, 512, 0, stream>>>(qb, nullptr, wot, nullptr, nullptr, lat, nullptr, 512, 512, 2, 0);
    rms_rows<0><<<8192, 256, 0, stream>>>(lat, ca_ln + b * 1536 + 1024, xn);
    gemm256d<3, 0, 0><<<2048, 512, 0, stream>>>(xn, nullptr, w1t, h2, nullptr, nullptr, nullptr, 4096, 512, 16, 0);
    gemm256d<2, 0, 0><<<256, 512, 0, stream>>>(h2, nullptr, w2t, nullptr, nullptr, lat, nullptr, 512, 2048, 2, 0);

    // ---- temporal attention ----
    rms_rows<1><<<8192, 256, 0, stream>>>(lat, ta_ln + b * 1024, xn);
    gemm256d<4, 0, 0><<<768, 512, 0, stream>>>(xn, nullptr, tqkvt, qb, takv, nullptr, ta_bk + b * 512, 1536, 512, 6, 0);
    attn_ta<<<dim3(256, 8), 256, 0, stream>>>(qb, takv, cosT, sinT, qb);
    gemm256d<2, 1, 0><<<256, 512, 0, stream>>>(qb, nullptr, twot, nullptr, nullptr, lat, nullptr, 512, 512, 2, 0);
    rms_rows<1><<<8192, 256, 0, stream>>>(lat, ta_ln + b * 1024 + 512, xn);
    gemm256d<3, 0, 0><<<2048, 512, 0, stream>>>(xn, nullptr, tw1t, h2, nullptr, nullptr, nullptr, 4096, 512, 16, 0);
    gemm256d<2, 1, 0><<<256, 512, 0, stream>>>(h2, nullptr, tw2t, nullptr, nullptr, lat, nullptr, 512, 2048, 2, 0);
  }
}

// Round 16
// 4431.670 us; speedup vs baseline: 1.0649x; 1.0649x over previous
//
#include <hip/hip_runtime.h>
#include <stdint.h>

// ---------------------------------------------------------------------------
// SpatioTemporalPerceiverResampler  (D=512, H=8, DH=64, NB=4, DMLP=2048,
// L=32, T=128, B=8, BT=1024, ROPE_DIM=32)
// R16 = R14 restore (best state, 4443 us; R15's 32x32 MFMA reverted: its
// operand layout is a structural 4-way LDS bank conflict -- 32 rows per b128
// group, 8 XOR keys -- measured 1.26e7 conflicts, -10%).
// gemm256d: 16x16x32 MFMA, 256x256 tile, compile-time slot parity, drift TLP
// (no mid-tile barriers), XOR swizzle, setprio, XCD swizzle. Register-softmax
// attention (R6). Fused CA-KV / TA-QKV projections.
// ---------------------------------------------------------------------------

typedef short    bf16x8 __attribute__((ext_vector_type(8)));
typedef float    f32x4  __attribute__((ext_vector_type(4)));
typedef uint16_t u16;

__device__ __forceinline__ float bf2f(uint32_t u) {
  union { uint32_t i; float f; } x; x.i = u << 16; return x.f;
}
__device__ __forceinline__ u16 f2bf(float f) {
  union { float f; uint32_t i; } x; x.f = f;
  return (u16)((x.i + 0x7fffu + ((x.i >> 16) & 1u)) >> 16);  // RNE
}
__device__ __forceinline__ float gelu_t(float x) {  // jax.nn.gelu approximate=True
  float u = 0.7978845608028654f * (x + 0.044715f * x * x * x);
  float t = 1.f - 2.f / (__expf(2.f * u) + 1.f);
  return 0.5f * x * (1.f + t);
}
// r_x = (b*L + l)*T + t  ->  lat row (b*T + t)*L + l     (L=32, T=128)
template<int RMAP>
__device__ __forceinline__ int maprow(int r) {
  if (RMAP == 0) return r;
  int b = r >> 12, rem = r & 4095;
  return ((b << 7) + (rem & 127)) * 32 + (rem >> 7);
}
__device__ __forceinline__ void glds16(const u16* g, u16* l) {
  __builtin_amdgcn_global_load_lds((const __attribute__((address_space(1))) uint32_t*)(g),
                                   (__attribute__((address_space(3))) uint32_t*)(l),
                                   16, 0, 0);
}

// ---------------------------------------------------------------------------
__global__ __launch_bounds__(256) void transpose_cast(const float* __restrict__ src,
                                                      u16* __restrict__ dst,
                                                      int R, int C, size_t zsD) {
  src += (size_t)blockIdx.z * R * C;
  dst += (size_t)blockIdx.z * zsD;
  __shared__ float t[32][33];
  int c0 = blockIdx.x * 32, r0 = blockIdx.y * 32;
  int tx = threadIdx.x & 31, ty = threadIdx.x >> 5;
#pragma unroll
  for (int i = 0; i < 32; i += 8) t[ty + i][tx] = src[(size_t)(r0 + ty + i) * C + c0 + tx];
  __syncthreads();
#pragma unroll
  for (int i = 0; i < 32; i += 8)
    dst[(size_t)(c0 + ty + i) * R + r0 + tx] = f2bf(t[tx][ty + i]);
}

// w1 (512 x 4096) -> w1t (4096 x 512), GEGLU interleave for the 256-wide tile
// (R8-proven): dst row c: src col (c>>8)*128 + ((c>>6)&3)*32 + (c&31)
//              + (c&32 ? 2048 : 0)
__global__ __launch_bounds__(256) void transpose_w1(const float* __restrict__ src,
                                                    u16* __restrict__ dst) {
  src += (size_t)blockIdx.z * 512 * 4096;
  dst += (size_t)blockIdx.z * 512 * 4096;
  __shared__ float t[32][33];
  int c0 = blockIdx.x * 32, r0 = blockIdx.y * 32;
  int m0 = (c0 >> 8) * 128 + ((c0 >> 6) & 3) * 32 + ((c0 & 32) ? 2048 : 0);
  int tx = threadIdx.x & 31, ty = threadIdx.x >> 5;
#pragma unroll
  for (int i = 0; i < 32; i += 8) t[ty + i][tx] = src[(size_t)(r0 + ty + i) * 4096 + m0 + tx];
  __syncthreads();
#pragma unroll
  for (int i = 0; i < 32; i += 8)
    dst[(size_t)(c0 + ty + i) * 512 + r0 + tx] = f2bf(t[tx][ty + i]);
}

// ---------------------------------------------------------------------------
__global__ void rope_init(float* cosT, float* sinT) {
  int idx = blockIdx.x * 256 + threadIdx.x;
  if (idx < 128 * 16) {
    int t = idx >> 4, j = idx & 15;
    float inv = __expf(-logf(10000.f) * (float)j / 16.f);
    float a = (float)t * inv;
    cosT[idx] = cosf(a);
    sinT[idx] = sinf(a);
  }
}

__global__ __launch_bounds__(256) void init_lat(const float* __restrict__ ql,
                                                float* __restrict__ lat) {
  size_t i = (size_t)blockIdx.x * 256 + threadIdx.x;  // float4 index
  int r = (int)(i >> 7), cw = (int)(i & 127);
  int l = r & 31;
  ((float4*)lat)[i] = ((const float4*)ql)[l * 128 + cw];
}

// ---------------------------------------------------------------------------
// rms helper (one wave per row of 512)
__device__ __forceinline__ void rms_row_body(const float* __restrict__ src,
                                             const float* __restrict__ g,
                                             u16* __restrict__ out,
                                             int srow, int orow, int lane) {
  const float4* p = (const float4*)(src + (size_t)srow * 512);
  float4 v0 = p[lane * 2], v1 = p[lane * 2 + 1];
  float ss = v0.x * v0.x + v0.y * v0.y + v0.z * v0.z + v0.w * v0.w +
             v1.x * v1.x + v1.y * v1.y + v1.z * v1.z + v1.w * v1.w;
#pragma unroll
  for (int m = 1; m < 64; m <<= 1) ss += __shfl_xor(ss, m);
  const float rs = rsqrtf(ss * (1.f / 512.f) + 1e-6f);
  const float4* gp = (const float4*)g;
  float4 g0 = gp[lane * 2], g1 = gp[lane * 2 + 1];
  u16 rb[8];
  rb[0] = f2bf(v0.x * rs * g0.x); rb[1] = f2bf(v0.y * rs * g0.y);
  rb[2] = f2bf(v0.z * rs * g0.z); rb[3] = f2bf(v0.w * rs * g0.w);
  rb[4] = f2bf(v1.x * rs * g1.x); rb[5] = f2bf(v1.y * rs * g1.y);
  rb[6] = f2bf(v1.z * rs * g1.z); rb[7] = f2bf(v1.w * rs * g1.w);
  *(int4*)(out + (size_t)orow * 512 + lane * 8) = *(int4*)rb;
}

template<int RMAP>
__global__ __launch_bounds__(256) void rms_rows(const float* __restrict__ src,
                                                const float* __restrict__ g,
                                                u16* __restrict__ out) {
  const int wid = threadIdx.x >> 6, lane = threadIdx.x & 63;
  const int row = (blockIdx.x << 2) + wid;
  rms_row_body(src, g, out, maprow<RMAP>(row), row, lane);
}

// merged CA norms: blocks [0,8192): l_n (lat->xn, g0); [8192,24576): s_n
// (source->shat, g1).
__global__ __launch_bounds__(256) void rms_ca(const float* __restrict__ lat,
                                              const float* __restrict__ source,
                                              const float* __restrict__ g0,
                                              const float* __restrict__ g1,
                                              u16* __restrict__ xn,
                                              u16* __restrict__ shat) {
  const int wid = threadIdx.x >> 6, lane = threadIdx.x & 63;
  if (blockIdx.x < 8192) {
    const int row = (blockIdx.x << 2) + wid;
    rms_row_body(lat, g0, xn, row, row, lane);
  } else {
    const int row = ((blockIdx.x - 8192) << 2) + wid;
    rms_row_body(source, g1, shat, row, row, lane);
  }
}

// ---------------------------------------------------------------------------
// gemm256d (R13 K-loop, runtime ntn): 256x256 tile, BK=64, 8 waves, per-wave
// C 128x64. Double-buffered A/B, compile-time slot parity (K-loop unrolled
// x2), frag ping-pong one phase ahead, NO mid-tile barriers, gate =
// vmcnt(0)+barrier per K-tile. XOR swizzle, setprio, XCD swizzle.
// EPI: 0 bf16; 1 +bias cols<512; 2 latF[maprow]+=; 3 GEGLU->h2[.][2048];
//      4 TA QKV route: col<512 -> outH(q, stride 512); 512-1023 ->
//      outH2(k half, +bias); >=1024 -> outH2(v half). AMAP: 1 = CA kv map.
// ---------------------------------------------------------------------------
template<int EPI, int RMAP, int AMAP>
__global__ __launch_bounds__(512, 2) void gemm256d(const u16* __restrict__ A,
                                                   const u16* __restrict__ A2,
                                                   const u16* __restrict__ Bt,
                                                   u16* __restrict__ outH,
                                                   u16* __restrict__ outH2,
                                                   float* __restrict__ latF,
                                                   const float* __restrict__ bias,
                                                   int N, int K, int ntn, int nb) {
  __shared__ __align__(16) u16 Ab[2][256 * 64];   // 64 KiB
  __shared__ __align__(16) u16 Bb[2][256 * 64];   // 64 KiB
  const int tid = threadIdx.x;
  const int NBk = gridDim.x;
  const int sb = (blockIdx.x & 7) * (NBk >> 3) + (blockIdx.x >> 3);  // XCD swz
  const int m0 = (sb / ntn) << 8;
  const int n0 = (sb % ntn) << 8;
  const int wid = tid >> 6, lane = tid & 63;
  const int wm = wid >> 2, wn = wid & 3;
  const int lr = lane & 15, lg = lane >> 4;
  const int rx = (lr & 7) << 3;
  const int nkt = K >> 6;   // even for all shapes used (8 or 32)

  auto stageA = [&](int kt, int slot, int h) {
#pragma unroll
    for (int i = 0; i < 2; ++i) {
      const int e = ((h * 2 + i) * 512 + tid) * 8;
      const int r = e >> 6;
      const int cs = (e & 63) ^ ((r & 7) << 3);
      const u16* src;
      if constexpr (AMAP == 0) {
        src = A + (size_t)(m0 + r) * K + kt * 64 + cs;
      } else {
        const int R = m0 + r;
        const int n_ = R / 96;
        const int j = R - n_ * 96;
        src = (j < 64) ? A  + ((size_t)((nb + n_) * 64 + j)) * 512 + kt * 64 + cs
                       : A2 + ((size_t)((nb + n_) * 32 + (j - 64))) * 512 + kt * 64 + cs;
      }
      glds16(src, &Ab[slot][e]);
    }
  };
  auto stageB = [&](int kt, int slot, int h) {
#pragma unroll
    for (int i = 0; i < 2; ++i) {
      const int e = ((h * 2 + i) * 512 + tid) * 8;
      const int r = e >> 6;
      const int cs = (e & 63) ^ ((r & 7) << 3);
      glds16(Bt + (size_t)(n0 + r) * K + kt * 64 + cs, &Bb[slot][e]);
    }
  };

  bf16x8 bfr[2][4];
  bf16x8 afrA[2][2], afrB_[2][2];
  auto readAfr = [&](bf16x8 (&dst)[2][2], const u16* Abase, int p) {
#pragma unroll
    for (int d = 0; d < 2; ++d)
#pragma unroll
      for (int ks = 0; ks < 2; ++ks) {
        const int rw = wm * 128 + (p * 2 + d) * 16 + lr;
        dst[d][ks] = *(const bf16x8*)&Abase[rw * 64 + ((ks * 32 + lg * 8) ^ rx)];
      }
  };
  auto readBfr = [&](const u16* Bbase) {
#pragma unroll
    for (int ks = 0; ks < 2; ++ks)
#pragma unroll
      for (int in = 0; in < 4; ++in) {
        const int rw = wn * 64 + in * 16 + lr;
        bfr[ks][in] = *(const bf16x8*)&Bbase[rw * 64 + ((ks * 32 + lg * 8) ^ rx)];
      }
  };

  f32x4 acc[8][4];
#pragma unroll
  for (int i = 0; i < 8; ++i)
#pragma unroll
    for (int j = 0; j < 4; ++j) acc[i][j] = (f32x4){0.f, 0.f, 0.f, 0.f};

  // prologue: stage tile 0 into slot 0; drain; pre-read frags.
  stageA(0, 0, 0); stageA(0, 0, 1);
  stageB(0, 0, 0); stageB(0, 0, 1);
  asm volatile("s_waitcnt vmcnt(0)" ::: "memory");
  __builtin_amdgcn_s_barrier();
  asm volatile("" ::: "memory");
  readBfr(&Bb[0][0]);
  readAfr(afrA, &Ab[0][0], 0);

  for (int kt0 = 0; kt0 < nkt; kt0 += 2) {
#pragma unroll
    for (int par = 0; par < 2; ++par) {       // par == buffer slot (compile-time)
      const int vk = kt0 + par;
      const u16* Abase = &Ab[par][0];
      const bool pf = (vk + 1 < nkt);
#pragma unroll
      for (int p = 0; p < 4; ++p) {
        if (p == 0 && pf) { stageB(vk + 1, par ^ 1, 0); stageB(vk + 1, par ^ 1, 1); }
        if (p == 1 && pf) { stageA(vk + 1, par ^ 1, 0); stageA(vk + 1, par ^ 1, 1); }
        if (p < 3) {
          if ((p & 1) == 0) readAfr(afrB_, Abase, p + 1);
          else              readAfr(afrA,  Abase, p + 1);
        }
        __builtin_amdgcn_s_setprio(1);
        if ((p & 1) == 0) {
#pragma unroll
          for (int d = 0; d < 2; ++d)
#pragma unroll
            for (int in = 0; in < 4; ++in)
#pragma unroll
              for (int ks = 0; ks < 2; ++ks)
                acc[p * 2 + d][in] = __builtin_amdgcn_mfma_f32_16x16x32_bf16(
                    afrA[d][ks], bfr[ks][in], acc[p * 2 + d][in], 0, 0, 0);
        } else {
#pragma unroll
          for (int d = 0; d < 2; ++d)
#pragma unroll
            for (int in = 0; in < 4; ++in)
#pragma unroll
              for (int ks = 0; ks < 2; ++ks)
                acc[p * 2 + d][in] = __builtin_amdgcn_mfma_f32_16x16x32_bf16(
                    afrB_[d][ks], bfr[ks][in], acc[p * 2 + d][in], 0, 0, 0);
        }
        __builtin_amdgcn_s_setprio(0);
        // no mid-tile barriers (R12 win); gate per K-tile:
        if (p == 3 && pf) {
          asm volatile("s_waitcnt vmcnt(0)" ::: "memory");
          __builtin_amdgcn_s_barrier();
          asm volatile("" ::: "memory");
          readBfr(&Bb[par ^ 1][0]);
          readAfr(afrA, &Ab[par ^ 1][0], 0);
        }
      }
    }
  }

  // ---- epilogue ----
  if constexpr (EPI == 3) {
    const int t128 = n0 >> 1;
#pragma unroll
    for (int im = 0; im < 8; ++im)
#pragma unroll
      for (int in = 0; in < 2; ++in)
#pragma unroll
        for (int j = 0; j < 4; ++j) {
          const int row = m0 + wm * 128 + im * 16 + lg * 4 + j;
          const int hcol = t128 + wn * 32 + in * 16 + lr;
          outH[(size_t)row * 2048 + hcol] = f2bf(acc[im][in][j] * gelu_t(acc[im][in + 2][j]));
        }
  } else if constexpr (EPI == 2) {
#pragma unroll
    for (int im = 0; im < 8; ++im)
#pragma unroll
      for (int in = 0; in < 4; ++in) {
        const int col = n0 + wn * 64 + in * 16 + lr;
#pragma unroll
        for (int j = 0; j < 4; ++j) {
          const int row = m0 + wm * 128 + im * 16 + lg * 4 + j;
          const size_t rr = (size_t)maprow<RMAP>(row) * 512 + col;
          latF[rr] += acc[im][in][j];
        }
      }
  } else if constexpr (EPI == 4) {
    // TA QKV route (block-uniform: n0 in {0,256,512,768,1024,1280})
    float bv4[4];
#pragma unroll
    for (int in = 0; in < 4; ++in) {
      const int col = n0 + wn * 64 + in * 16 + lr;
      bv4[in] = (col >= 512 && col < 1024) ? bias[col - 512] : 0.f;
    }
#pragma unroll
    for (int im = 0; im < 8; ++im)
#pragma unroll
      for (int in = 0; in < 4; ++in) {
        const int col = n0 + wn * 64 + in * 16 + lr;
#pragma unroll
        for (int j = 0; j < 4; ++j) {
          const int row = m0 + wm * 128 + im * 16 + lg * 4 + j;
          const float v = acc[im][in][j] + bv4[in];
          if (col < 512) outH[(size_t)row * 512 + col] = f2bf(v);
          else           outH2[(size_t)row * 1024 + col - 512] = f2bf(v);
        }
      }
  } else {
    float bv4[4];
    if constexpr (EPI == 1) {
#pragma unroll
      for (int in = 0; in < 4; ++in)
        bv4[in] = (n0 < 512) ? bias[n0 + wn * 64 + in * 16 + lr] : 0.f;
    }
#pragma unroll
    for (int im = 0; im < 8; ++im)
#pragma unroll
      for (int in = 0; in < 4; ++in) {
        const int col = n0 + wn * 64 + in * 16 + lr;
#pragma unroll
        for (int j = 0; j < 4; ++j) {
          const int row = m0 + wm * 128 + im * 16 + lg * 4 + j;
          float v = acc[im][in][j];
          if constexpr (EPI == 1) v += bv4[in];
          outH[(size_t)row * N + col] = f2bf(v);
        }
      }
  }
}

// ---------------------------------------------------------------------------
// Cross-attention R6: block per (n_local,h), n = nb + n_local. Lq=32, Lk=96.
// ---------------------------------------------------------------------------
__global__ __launch_bounds__(256) void attn_ca(const u16* q,
                                               const u16* __restrict__ kv,
                                               u16* o, int nb) {
  union __align__(16) SM {
    struct { u16 Qs[32][72]; u16 Ks[96][72]; } qk;
    u16 Pb[32][104];
  };
  __shared__ SM sm;
  __shared__ __align__(16) u16 Vt[64][104];
  __shared__ float pmax[2][32];
  __shared__ float psum[2][32];
  const int nl = blockIdx.x, n = nb + nl, h = blockIdx.y, tid = threadIdx.x;

  {
    int r = tid >> 3, c = (tid & 7) * 8;
    *(int4*)&sm.qk.Qs[r][c] = *(const int4*)&q[((size_t)n * 32 + r) * 512 + h * 64 + c];
  }
#pragma unroll
  for (int i = 0; i < 3; ++i) {
    int idx = i * 256 + tid;
    int r = idx >> 3, c = (idx & 7) * 8;
    *(int4*)&sm.qk.Ks[r][c] = *(const int4*)&kv[((size_t)nl * 96 + r) * 1024 + h * 64 + c];
  }
#pragma unroll
  for (int i = 0; i < 3; ++i) {
    int idx = i * 256 + tid;
    int dg = idx / 96, t = idx - dg * 96;
    int4 pv = *(const int4*)&kv[((size_t)nl * 96 + t) * 1024 + 512 + h * 64 + dg * 8];
    const u16* pu = (const u16*)&pv;
#pragma unroll
    for (int e = 0; e < 8; ++e) Vt[dg * 8 + e][t] = pu[e];
  }
  __syncthreads();

  const int wid = tid >> 6, lane = tid & 63, lr = lane & 15, lg = lane >> 4;
  const int m0 = (wid & 1) * 16, wnq = wid >> 1, nbc = wnq * 48;

  f32x4 sa[3];
#pragma unroll
  for (int f = 0; f < 3; ++f) sa[f] = (f32x4){0.f, 0.f, 0.f, 0.f};
#pragma unroll
  for (int ks = 0; ks < 2; ++ks) {
    bf16x8 a = *(const bf16x8*)&sm.qk.Qs[m0 + lr][ks * 32 + lg * 8];
#pragma unroll
    for (int f = 0; f < 3; ++f) {
      bf16x8 bb = *(const bf16x8*)&sm.qk.Ks[nbc + f * 16 + lr][ks * 32 + lg * 8];
      sa[f] = __builtin_amdgcn_mfma_f32_16x16x32_bf16(a, bb, sa[f], 0, 0, 0);
    }
  }

#pragma unroll
  for (int j = 0; j < 4; ++j) {
    float m = fmaxf(fmaxf(sa[0][j], sa[1][j]), sa[2][j]);
    m = fmaxf(m, __shfl_xor(m, 1));
    m = fmaxf(m, __shfl_xor(m, 2));
    m = fmaxf(m, __shfl_xor(m, 4));
    m = fmaxf(m, __shfl_xor(m, 8));
    if (lr == 0) pmax[wnq][m0 + lg * 4 + j] = m;
  }
  __syncthreads();
#pragma unroll
  for (int j = 0; j < 4; ++j) {
    const int row = m0 + lg * 4 + j;
    const float m = fmaxf(pmax[0][row], pmax[1][row]);
    float s = 0.f;
#pragma unroll
    for (int f = 0; f < 3; ++f) {
      float p = __expf(0.125f * (sa[f][j] - m));
      sa[f][j] = p;
      s += p;
    }
    s += __shfl_xor(s, 1); s += __shfl_xor(s, 2); s += __shfl_xor(s, 4); s += __shfl_xor(s, 8);
    if (lr == 0) psum[wnq][row] = s;
  }
#pragma unroll
  for (int f = 0; f < 3; ++f)
#pragma unroll
    for (int j = 0; j < 4; ++j)
      sm.Pb[m0 + lg * 4 + j][nbc + f * 16 + lr] = f2bf(sa[f][j]);
  __syncthreads();

  const int n0d = wnq * 32;
  f32x4 oa[2];
#pragma unroll
  for (int f = 0; f < 2; ++f) oa[f] = (f32x4){0.f, 0.f, 0.f, 0.f};
#pragma unroll
  for (int ks = 0; ks < 3; ++ks) {
    bf16x8 a = *(const bf16x8*)&sm.Pb[m0 + lr][ks * 32 + lg * 8];
#pragma unroll
    for (int f = 0; f < 2; ++f) {
      bf16x8 bb = *(const bf16x8*)&Vt[n0d + f * 16 + lr][ks * 32 + lg * 8];
      oa[f] = __builtin_amdgcn_mfma_f32_16x16x32_bf16(a, bb, oa[f], 0, 0, 0);
    }
  }
#pragma unroll
  for (int j = 0; j < 4; ++j) {
    const int row = m0 + lg * 4 + j;
    const float inv = 1.f / (psum[0][row] + psum[1][row]);
#pragma unroll
    for (int f = 0; f < 2; ++f)
      o[((size_t)n * 32 + row) * 512 + h * 64 + n0d + f * 16 + lr] = f2bf(oa[f][j] * inv);
  }
}

// ---------------------------------------------------------------------------
// Temporal attention R6 with RoPE: block per (n,h), n in [0,256). T=128.
// ---------------------------------------------------------------------------
__global__ __launch_bounds__(256) void attn_ta(const u16* q,
                                               const u16* __restrict__ kv,
                                               const float* __restrict__ cosT,
                                               const float* __restrict__ sinT,
                                               u16* o) {
  union __align__(16) SM {
    struct { u16 Qs[128][72]; u16 Ks[128][72]; } qk;
    u16 Pb[128][136];
  };
  __shared__ SM sm;
  __shared__ __align__(16) u16 Vt[64][136];
  __shared__ float pmax[2][128];
  __shared__ float psum[2][128];
  const int n = blockIdx.x, h = blockIdx.y, tid = threadIdx.x;

#pragma unroll
  for (int i = 0; i < 16; ++i) {
    int idx = i * 256 + tid;
    int t = idx >> 5, pr = idx & 31;
    uint32_t uq = *(const uint32_t*)&q[((size_t)n * 128 + t) * 512 + h * 64 + pr * 2];
    uint32_t uk = *(const uint32_t*)&kv[((size_t)n * 128 + t) * 1024 + h * 64 + pr * 2];
    float q1 = bf2f(uq & 0xffff), q2 = bf2f(uq >> 16);
    float k1 = bf2f(uk & 0xffff), k2 = bf2f(uk >> 16);
    if (pr < 16) {
      float c = cosT[t * 16 + pr], s = sinT[t * 16 + pr];
      float a;
      a = q1 * c - q2 * s; q2 = q1 * s + q2 * c; q1 = a;
      a = k1 * c - k2 * s; k2 = k1 * s + k2 * c; k1 = a;
    }
    sm.qk.Qs[t][pr * 2] = f2bf(q1); sm.qk.Qs[t][pr * 2 + 1] = f2bf(q2);
    sm.qk.Ks[t][pr * 2] = f2bf(k1); sm.qk.Ks[t][pr * 2 + 1] = f2bf(k2);
  }
#pragma unroll
  for (int i = 0; i < 4; ++i) {
    int idx = i * 256 + tid;
    int t = idx & 127, d0 = (idx >> 7) * 8;
    int4 pv = *(const int4*)&kv[((size_t)n * 128 + t) * 1024 + 512 + h * 64 + d0];
    const u16* pu = (const u16*)&pv;
#pragma unroll
    for (int e = 0; e < 8; ++e) Vt[d0 + e][t] = pu[e];
  }
  __syncthreads();

  const int wid = tid >> 6, lane = tid & 63, lr = lane & 15, lg = lane >> 4;
  const int wm = wid >> 1, wn = wid & 1;
  const int rbase = wm * 64;

  f32x4 sa[4][4];
#pragma unroll
  for (int i = 0; i < 4; ++i)
#pragma unroll
    for (int j = 0; j < 4; ++j) sa[i][j] = (f32x4){0.f, 0.f, 0.f, 0.f};
#pragma unroll
  for (int ks = 0; ks < 2; ++ks) {
    bf16x8 av[4], bv[4];
#pragma unroll
    for (int im = 0; im < 4; ++im)
      av[im] = *(const bf16x8*)&sm.qk.Qs[rbase + im * 16 + lr][ks * 32 + lg * 8];
#pragma unroll
    for (int in = 0; in < 4; ++in)
      bv[in] = *(const bf16x8*)&sm.qk.Ks[wn * 64 + in * 16 + lr][ks * 32 + lg * 8];
#pragma unroll
    for (int im = 0; im < 4; ++im)
#pragma unroll
      for (int in = 0; in < 4; ++in)
        sa[im][in] = __builtin_amdgcn_mfma_f32_16x16x32_bf16(av[im], bv[in], sa[im][in], 0, 0, 0);
  }

#pragma unroll
  for (int im = 0; im < 4; ++im)
#pragma unroll
    for (int j = 0; j < 4; ++j) {
      float m = fmaxf(fmaxf(sa[im][0][j], sa[im][1][j]), fmaxf(sa[im][2][j], sa[im][3][j]));
      m = fmaxf(m, __shfl_xor(m, 1));
      m = fmaxf(m, __shfl_xor(m, 2));
      m = fmaxf(m, __shfl_xor(m, 4));
      m = fmaxf(m, __shfl_xor(m, 8));
      if (lr == 0) pmax[wn][rbase + im * 16 + lg * 4 + j] = m;
    }
  __syncthreads();
#pragma unroll
  for (int im = 0; im < 4; ++im)
#pragma unroll
    for (int j = 0; j < 4; ++j) {
      const int row = rbase + im * 16 + lg * 4 + j;
      const float m = fmaxf(pmax[0][row], pmax[1][row]);
      float s = 0.f;
#pragma unroll
      for (int in = 0; in < 4; ++in) {
        float p = __expf(0.125f * (sa[im][in][j] - m));
        sa[im][in][j] = p;
        s += p;
      }
      s += __shfl_xor(s, 1); s += __shfl_xor(s, 2); s += __shfl_xor(s, 4); s += __shfl_xor(s, 8);
      if (lr == 0) psum[wn][row] = s;
    }
#pragma unroll
  for (int im = 0; im < 4; ++im)
#pragma unroll
    for (int in = 0; in < 4; ++in)
#pragma unroll
      for (int j = 0; j < 4; ++j)
        sm.Pb[rbase + im * 16 + lg * 4 + j][wn * 64 + in * 16 + lr] = f2bf(sa[im][in][j]);
  __syncthreads();

  f32x4 oa[2][4];
#pragma unroll
  for (int i = 0; i < 2; ++i)
#pragma unroll
    for (int j = 0; j < 4; ++j) oa[i][j] = (f32x4){0.f, 0.f, 0.f, 0.f};
#pragma unroll
  for (int ks = 0; ks < 4; ++ks) {
    bf16x8 av[2], bv[4];
#pragma unroll
    for (int im = 0; im < 2; ++im)
      av[im] = *(const bf16x8*)&sm.Pb[wid * 32 + im * 16 + lr][ks * 32 + lg * 8];
#pragma unroll
    for (int in = 0; in < 4; ++in)
      bv[in] = *(const bf16x8*)&Vt[in * 16 + lr][ks * 32 + lg * 8];
#pragma unroll
    for (int im = 0; im < 2; ++im)
#pragma unroll
      for (int in = 0; in < 4; ++in)
        oa[im][in] = __builtin_amdgcn_mfma_f32_16x16x32_bf16(av[im], bv[in], oa[im][in], 0, 0, 0);
  }
#pragma unroll
  for (int im = 0; im < 2; ++im)
#pragma unroll
    for (int j = 0; j < 4; ++j) {
      const int qi = wid * 32 + im * 16 + lg * 4 + j;
      const float inv = 1.f / (psum[0][qi] + psum[1][qi]);
#pragma unroll
      for (int in = 0; in < 4; ++in)
        o[((size_t)n * 128 + qi) * 512 + h * 64 + in * 16 + lr] = f2bf(oa[im][in][j] * inv);
    }
}

// ---------------------------------------------------------------------------
extern "C" void kernel_launch(void* const* d_in, const int* in_sizes, int n_in,
                              void* d_out, int out_size, void* d_ws, size_t ws_size,
                              hipStream_t stream) {
  const float* source = (const float*)d_in[0];
  const float* qlat   = (const float*)d_in[1];
  const float* ca_ln  = (const float*)d_in[2];
  const float* ca_wq  = (const float*)d_in[3];
  const float* ca_wk  = (const float*)d_in[4];
  const float* ca_bk  = (const float*)d_in[5];
  const float* ca_wv  = (const float*)d_in[6];
  const float* ca_wo  = (const float*)d_in[7];
  const float* ca_w1  = (const float*)d_in[8];
  const float* ca_w2  = (const float*)d_in[9];
  const float* ta_ln  = (const float*)d_in[10];
  const float* ta_wq  = (const float*)d_in[11];
  const float* ta_wk  = (const float*)d_in[12];
  const float* ta_bk  = (const float*)d_in[13];
  const float* ta_wv  = (const float*)d_in[14];
  const float* ta_wo  = (const float*)d_in[15];
  const float* ta_w1  = (const float*)d_in[16];
  const float* ta_w2  = (const float*)d_in[17];
  float* lat = (float*)d_out;  // residual stream lives in d_out
  char* ws = (char*)d_ws;
  (void)in_sizes; (void)n_in; (void)out_size;

  if (ws_size < 251674624ull) return;  // known-good guard from R2

  const size_t WQ = 512 * 512, W1SZ = (size_t)512 * 4096, W2SZ = (size_t)2048 * 512;
  const size_t O_CA_WQ = 0,
               O_CA_KV = 4 * WQ,
               O_CA_WO = 12 * WQ,
               O_CA_W1 = 16 * WQ,
               O_CA_W2 = O_CA_W1 + 4 * W1SZ,
               O_TA_QKV = O_CA_W2 + 4 * W2SZ,      // [wq|wk|wv] per block, 3WQ each
               O_TA_WO = O_TA_QKV + 12 * WQ,
               O_TA_W1 = O_TA_WO + 4 * WQ,
               O_TA_W2 = O_TA_W1 + 4 * W1SZ;  // ends at 128*WQ = 67,108,864 B

  u16*   W    = (u16*)ws;                    // [0, 67,108,864)  weights (exact)
  u16*   xn   = (u16*)(ws + 67108864);       // 32 MiB
  u16*   shat = (u16*)(ws + 100663296);      // 64 MiB (CA s_n; TA fused KV; h2 head)
  u16*   qb   = (u16*)(ws + 167772160);      // 32 MiB (q / attn out)
  u16*   kvb  = (u16*)(ws + 201326592);      // 48 MiB (CA fused K|V chunk)
  u16*   h2   = shat;                        // MLP hidden 128 MiB
  u16*   takv = shat;                        // TA fused KV 64 MiB
  float* cosT = (float*)(ws + 251658240);    // 8 KiB  (tail gap, within guard)
  float* sinT = (float*)(ws + 251666432);    // 8 KiB

  transpose_cast<<<dim3(16, 16, 4), 256, 0, stream>>>(ca_wq, W + O_CA_WQ, 512, 512, WQ);
  transpose_cast<<<dim3(16, 16, 4), 256, 0, stream>>>(ca_wk, W + O_CA_KV, 512, 512, 2 * WQ);
  transpose_cast<<<dim3(16, 16, 4), 256, 0, stream>>>(ca_wv, W + O_CA_KV + WQ, 512, 512, 2 * WQ);
  transpose_cast<<<dim3(16, 16, 4), 256, 0, stream>>>(ca_wo, W + O_CA_WO, 512, 512, WQ);
  transpose_w1 <<<dim3(128, 16, 4), 256, 0, stream>>>(ca_w1, W + O_CA_W1);
  transpose_cast<<<dim3(16, 64, 4), 256, 0, stream>>>(ca_w2, W + O_CA_W2, 2048, 512, W2SZ);
  transpose_cast<<<dim3(16, 16, 4), 256, 0, stream>>>(ta_wq, W + O_TA_QKV, 512, 512, 3 * WQ);
  transpose_cast<<<dim3(16, 16, 4), 256, 0, stream>>>(ta_wk, W + O_TA_QKV + WQ, 512, 512, 3 * WQ);
  transpose_cast<<<dim3(16, 16, 4), 256, 0, stream>>>(ta_wv, W + O_TA_QKV + 2 * WQ, 512, 512, 3 * WQ);
  transpose_cast<<<dim3(16, 16, 4), 256, 0, stream>>>(ta_wo, W + O_TA_WO, 512, 512, WQ);
  transpose_w1 <<<dim3(128, 16, 4), 256, 0, stream>>>(ta_w1, W + O_TA_W1);
  transpose_cast<<<dim3(16, 64, 4), 256, 0, stream>>>(ta_w2, W + O_TA_W2, 2048, 512, W2SZ);
  rope_init<<<8, 256, 0, stream>>>(cosT, sinT);
  init_lat<<<16384, 256, 0, stream>>>(qlat, lat);

  for (int b = 0; b < 4; ++b) {
    const u16* wqt   = W + O_CA_WQ + (size_t)b * WQ;
    const u16* wkvt  = W + O_CA_KV + (size_t)b * 2 * WQ;
    const u16* wot   = W + O_CA_WO + (size_t)b * WQ;
    const u16* w1t   = W + O_CA_W1 + (size_t)b * W1SZ;
    const u16* w2t   = W + O_CA_W2 + (size_t)b * W2SZ;
    const u16* tqkvt = W + O_TA_QKV + (size_t)b * 3 * WQ;
    const u16* twot  = W + O_TA_WO + (size_t)b * WQ;
    const u16* tw1t  = W + O_TA_W1 + (size_t)b * W1SZ;
    const u16* tw2t  = W + O_TA_W2 + (size_t)b * W2SZ;

    // ---- cross attention ----
    rms_ca<<<24576, 256, 0, stream>>>(lat, source, ca_ln + b * 1536, ca_ln + b * 1536 + 512, xn, shat);
    gemm256d<0, 0, 0><<<256, 512, 0, stream>>>(xn, nullptr, wqt, qb, nullptr, nullptr, nullptr, 512, 512, 2, 0);
    for (int c = 0; c < 4; ++c) {  // fused K|V + attention per 256-batch chunk
      gemm256d<1, 0, 1><<<384, 512, 0, stream>>>(shat, xn, wkvt, kvb, nullptr, nullptr, ca_bk + b * 512, 1024, 512, 4, c * 256);
      attn_ca<<<dim3(256, 8), 256, 0, stream>>>(qb, kvb, qb, c * 256);
    }
    gemm256d<2, 0, 0><<<256, 512, 0, stream>>>(qb, nullptr, wot, nullptr, nullptr, lat, nullptr, 512, 512, 2, 0);
    rms_rows<0><<<8192, 256, 0, stream>>>(lat, ca_ln + b * 1536 + 1024, xn);
    gemm256d<3, 0, 0><<<2048, 512, 0, stream>>>(xn, nullptr, w1t, h2, nullptr, nullptr, nullptr, 4096, 512, 16, 0);
    gemm256d<2, 0, 0><<<256, 512, 0, stream>>>(h2, nullptr, w2t, nullptr, nullptr, lat, nullptr, 512, 2048, 2, 0);

    // ---- temporal attention ----
    rms_rows<1><<<8192, 256, 0, stream>>>(lat, ta_ln + b * 1024, xn);
    gemm256d<4, 0, 0><<<768, 512, 0, stream>>>(xn, nullptr, tqkvt, qb, takv, nullptr, ta_bk + b * 512, 1536, 512, 6, 0);
    attn_ta<<<dim3(256, 8), 256, 0, stream>>>(qb, takv, cosT, sinT, qb);
    gemm256d<2, 1, 0><<<256, 512, 0, stream>>>(qb, nullptr, twot, nullptr, nullptr, lat, nullptr, 512, 512, 2, 0);
    rms_rows<1><<<8192, 256, 0, stream>>>(lat, ta_ln + b * 1024 + 512, xn);
    gemm256d<3, 0, 0><<<2048, 512, 0, stream>>>(xn, nullptr, tw1t, h2, nullptr, nullptr, nullptr, 4096, 512, 16, 0);
    gemm256d<2, 1, 0><<<256, 512, 0, stream>>>(h2, nullptr, tw2t, nullptr, nullptr, lat, nullptr, 512, 2048, 2, 0);
  }
}